// Round 15
// baseline (56.039 us; speedup 1.0000x reference)
//
#include <hip/hip_runtime.h>
#include <hip/hip_bf16.h>
#include <math.h>

#define NN    20000
#define NK    160000          // NN*8
#define NEDGE 320000
#define HID   256
#define INFEAT 128
#define EPSF  1e-5f
#define NT1   313             // 64-row tiles (fused1)
#define MOUT  104             // out-tile nodes per fused2 block
#define NT2B  193             // ceil(20000/104)

typedef __bf16  bf16x8 __attribute__((ext_vector_type(8)));
typedef float   f32x4  __attribute__((ext_vector_type(4)));
typedef ushort  u16x8  __attribute__((ext_vector_type(8)));

__device__ __forceinline__ float sigmoidf_(float x) { return 1.0f / (1.0f + expf(-x)); }

__device__ __forceinline__ ushort f2bf(float f) {
    __hip_bfloat16 h = __float2bfloat16(f);
    return __builtin_bit_cast(ushort, h);
}
__device__ __forceinline__ float bf2f(ushort u) {
    return __builtin_bit_cast(float, ((unsigned int)u) << 16);
}
__device__ __forceinline__ int wrapN(int v) {
    return (v < 0) ? v + NN : ((v >= NN) ? v - NN : v);
}

#define LDSP(p) ((__attribute__((address_space(3))) unsigned int*)(p))
#define GBLP(p) ((const __attribute__((address_space(1))) unsigned int*)(p))
#define GLD16(g, l) __builtin_amdgcn_global_load_lds(GBLP(g), LDSP(l), 16, 0, 0)

// ============ kernel 1: prep (W1t, W2t, zero asum), 49 blocks ============
__global__ __launch_bounds__(512, 2) void k_prep(const float* __restrict__ W1,
    const float* __restrict__ W2, ushort* __restrict__ W1t,
    ushort* __restrict__ W2t, float* __restrict__ asum)
{
    const int b = blockIdx.x, t = threadIdx.x;
    if (b < 16) {
        const int e = (b * 512 + t) * 4;            // W1t: 32768 elements
        ushort4 o;
        #pragma unroll
        for (int j = 0; j < 4; ++j) {
            const int ee = e + j;
            const int n = ee >> 7, k = ee & 127;    // W1t[n][k] = W1[k][n]
            ((ushort*)&o)[j] = f2bf(W1[k * 256 + n]);
        }
        *reinterpret_cast<ushort4*>(W1t + e) = o;
    } else if (b < 48) {
        const int e = ((b - 16) * 512 + t) * 4;     // W2t: 65536 elements
        ushort4 o;
        #pragma unroll
        for (int j = 0; j < 4; ++j) {
            const int ee = e + j;
            const int n = ee >> 8, k = ee & 255;    // W2t[n][k] = W2[k][n]
            ((ushort*)&o)[j] = f2bf(W2[k * 256 + n]);
        }
        *reinterpret_cast<ushort4*>(W2t + e) = o;
    } else {
        asum[t]       = 0.f;
        asum[512 + t] = 0.f;
    }
}

// ====== kernel 2: A = agg(x) @ W1 + b1 (agg fused in staging); BN partials -> asum ======
// 313 blocks x 512; tile 64(M) x 256(N), BK=64. xraw: 80 rows f32, 272B stride,
// 32B-group XOR swizzle g^( (row>>2)&7 ) (write & read matched).
__global__ __launch_bounds__(512, 2) void k_fused1(const float* __restrict__ x,
    const ushort* __restrict__ W1t, const float* __restrict__ b1,
    ushort* __restrict__ A, float* __restrict__ asum)
{
    __shared__ alignas(16) char smem[21760 + 8192 + 32768];
    char* xr = smem;                    // 80 x 272B (f32, padded+swizzled)
    char* As = smem + 21760;            // 64 x 128B (bf16, swizzled)
    char* Bs = smem + 21760 + 8192;     // 256 x 128B (bf16, swizzled)

    const int t = threadIdx.x;
    const int wave = t >> 6, lane = t & 63;
    const int wr = (wave >> 2) * 32;
    const int wc = (wave & 3) * 32;
    const int bm = blockIdx.x * 64;
    const float inv17 = 1.0f / 17.0f;
    f32x4 acc[2][2][2] = {};   // [ny][mi][ni]

    #pragma unroll
    for (int kt = 0; kt < 2; ++kt) {
        const int k0 = kt * 64;
        #pragma unroll
        for (int it = 0; it < 4; ++it) {   // stage B (async): 256x64 bf16, swizzled src
            const int cb = (it * 8 + wave) * 64 + lane;
            const int row = cb >> 3;
            const int lk = (cb & 7) ^ (row & 7);
            GLD16(W1t + (size_t)row * INFEAT + k0 + lk * 8, Bs + (it * 8 + wave) * 1024);
        }
        // reg-stage xraw: x rows [bm-8, bm+72) x 64 f32 cols (swizzled 32B groups)
        #pragma unroll
        for (int r3 = 0; r3 < 3; ++r3) {
            const int c = r3 * 512 + t;
            if (c < 1280) {
                const int row = c >> 4, cc = c & 15;
                const int g = cc >> 1, hf = cc & 1;
                const int pg = g ^ ((row >> 2) & 7);
                const int rg = wrapN(bm - 8 + row);
                const float4 v = *reinterpret_cast<const float4*>(
                    x + (size_t)rg * INFEAT + k0 + cc * 4);
                *reinterpret_cast<float4*>(xr + row * 272 + pg * 32 + hf * 16) = v;
            }
        }
        __syncthreads();
        if (t < 128) {   // As-build: depth-4 rolling, 16 q-groups x 8 c8
            const int q = t >> 3, c8 = t & 7;
            const int r0 = 4 * q;
            float S[8] = {};
            #pragma unroll
            for (int i = 0; i < 17; ++i) {
                const int r = r0 + i;
                const char* base = xr + r * 272 + ((c8 ^ ((r >> 2) & 7)) * 32);
                const float4 a  = *reinterpret_cast<const float4*>(base);
                const float4 bq = *reinterpret_cast<const float4*>(base + 16);
                S[0] += a.x;  S[1] += a.y;  S[2] += a.z;  S[3] += a.w;
                S[4] += bq.x; S[5] += bq.y; S[6] += bq.z; S[7] += bq.w;
            }
            #pragma unroll
            for (int jr = 0; jr < 4; ++jr) {
                const int l = r0 + jr;
                u16x8 o;
                #pragma unroll
                for (int j = 0; j < 8; ++j) o[j] = f2bf(S[j] * inv17);
                *reinterpret_cast<u16x8*>(As + l * 128 + ((c8 ^ (l & 7)) * 16)) = o;
                if (jr < 3) {
                    const int ra = l + 17, rs = l;
                    const char* ba = xr + ra * 272 + ((c8 ^ ((ra >> 2) & 7)) * 32);
                    const char* bs = xr + rs * 272 + ((c8 ^ ((rs >> 2) & 7)) * 32);
                    const float4 a0 = *reinterpret_cast<const float4*>(ba);
                    const float4 a1 = *reinterpret_cast<const float4*>(ba + 16);
                    const float4 s0 = *reinterpret_cast<const float4*>(bs);
                    const float4 s1 = *reinterpret_cast<const float4*>(bs + 16);
                    S[0] += a0.x - s0.x; S[1] += a0.y - s0.y;
                    S[2] += a0.z - s0.z; S[3] += a0.w - s0.w;
                    S[4] += a1.x - s1.x; S[5] += a1.y - s1.y;
                    S[6] += a1.z - s1.z; S[7] += a1.w - s1.w;
                }
            }
        }
        __syncthreads();
        #pragma unroll
        for (int kk = 0; kk < 2; ++kk) {
            const int klog = kk * 64 + ((lane >> 4) << 4);
            bf16x8 af[2];
            #pragma unroll
            for (int mi = 0; mi < 2; ++mi) {
                const int row = wr + mi * 16 + (lane & 15);
                af[mi] = *reinterpret_cast<const bf16x8*>(As + row * 128 + (klog ^ ((row & 7) << 4)));
            }
            #pragma unroll
            for (int ny = 0; ny < 2; ++ny)
                #pragma unroll
                for (int ni = 0; ni < 2; ++ni) {
                    const int row = ny * 128 + wc + ni * 16 + (lane & 15);
                    const bf16x8 bv = *reinterpret_cast<const bf16x8*>(Bs + row * 128 + (klog ^ ((row & 7) << 4)));
                    #pragma unroll
                    for (int mi = 0; mi < 2; ++mi)
                        acc[ny][mi][ni] = __builtin_amdgcn_mfma_f32_16x16x32_bf16(af[mi], bv, acc[ny][mi][ni], 0, 0, 0);
                }
        }
        __syncthreads();
    }

    // epilogue: bias, store A (bf16), BN partials -> global atomic accumulation
    float* sS  = (float*)smem;            // [8][64]
    float* s2S = (float*)(smem + 2048);   // [8][64]
    #pragma unroll
    for (int ny = 0; ny < 2; ++ny)
        #pragma unroll
        for (int ni = 0; ni < 2; ++ni) {
            const int colL = ny * 128 + wc + ni * 16 + (lane & 15);
            const float bv = b1[colL];
            float sv = 0.f, s2v = 0.f;
            #pragma unroll
            for (int mi = 0; mi < 2; ++mi)
                #pragma unroll
                for (int r = 0; r < 4; ++r) {
                    const int row = bm + wr + mi * 16 + ((lane >> 4) << 2) + r;
                    if (row < NN) {
                        const float val = acc[ny][mi][ni][r] + bv;
                        A[(size_t)row * 256 + colL] = f2bf(val);
                        sv += val; s2v += val * val;
                    }
                }
            sv  += __shfl_xor(sv, 16);  sv  += __shfl_xor(sv, 32);
            s2v += __shfl_xor(s2v, 16); s2v += __shfl_xor(s2v, 32);
            if (lane < 16) {
                sS [wave * 64 + ny * 32 + ni * 16 + lane] = sv;
                s2S[wave * 64 + ny * 32 + ni * 16 + lane] = s2v;
            }
        }
    __syncthreads();
    if (t < 256) {
        const int col = t;
        const int idx = (col >> 7) * 32 + ((col >> 4) & 1) * 16 + (col & 15);
        const int wcx = (col & 127) >> 5;
        atomicAdd(&asum[col],       sS [wcx * 64 + idx] + sS [(wcx + 4) * 64 + idx]);
        atomicAdd(&asum[512 + col], s2S[wcx * 64 + idx] + s2S[(wcx + 4) * 64 + idx]);
    }
}

// ===== kernel 3: h2 = relu( agg(relu(bn(A))) @ W2 + b2 ), dots, P, edge outputs =====
// Out-tile M=104; GEMM rows = 128 (halo recompute). Full Bs (256 rows); As-build
// rolling depth 8 with XOR-by-row-group swizzle on xr (write & read matched).
__global__ __launch_bounds__(512, 2) void k_fused2(const ushort* __restrict__ A,
    const ushort* __restrict__ W2t, const float* __restrict__ gamma,
    const float* __restrict__ beta, const float* __restrict__ b2,
    const float* __restrict__ Wl, const float* __restrict__ bl,
    const float* __restrict__ asum, float* __restrict__ out)
{
    __shared__ alignas(16) char smem[23040 + 16384 + 32768 + 2048];
    char* xr   = smem;                            // 144 x 160B (bf16 bnrelu'd, swizzled)
    char* As   = smem + 23040;                    // 128 x 128B swizzled
    char* Bs   = smem + 23040 + 16384;            // 256 x 128B swizzled (full N)
    float* ssS = (float*)(smem + 23040 + 16384 + 32768);  // sc[256] | sh[256]

    const int b = blockIdx.x, t = threadIdx.x;
    const int wave = t >> 6, lane = t & 63;
    const int wr  = (wave >> 1) * 32;       // 4 row-quads
    const int wcx = (wave & 1);             // 2 col groups of 64 within 128-half
    const int v0 = b * MOUT;
    const float inv17 = 1.0f / 17.0f;

    if (t < 256) {
        const float invn = 1.0f / (float)NN;
        const float mu  = asum[t] * invn;
        const float var = asum[512 + t] * invn - mu * mu;
        const float sc  = gamma[t] * rsqrtf(var + EPSF);
        ssS[t]       = sc;
        ssS[256 + t] = beta[t] - mu * sc;
    }
    __syncthreads();

    f32x4 acc[2][2][4] = {};   // [h][mi][ni]

    #pragma unroll
    for (int kt = 0; kt < 4; ++kt) {
        const int k0 = kt * 64;
        #pragma unroll
        for (int it = 0; it < 4; ++it) {   // stage B full (async): 256x64
            const int cb = (it * 8 + wave) * 64 + lane;
            const int row = cb >> 3;
            const int lk = (cb & 7) ^ (row & 7);
            GLD16(W2t + (size_t)row * 256 + k0 + lk * 8, Bs + (it * 8 + wave) * 1024);
        }
        // reg-stage xr = bnrelu(A rows wrapN(v0-16+row)): 1152 chunks, swizzled c8
        #pragma unroll
        for (int r3 = 0; r3 < 3; ++r3) {
            const int c = r3 * 512 + t;
            if (c < 1152) {
                const int row = c >> 3, c8 = c & 7;
                const int pc8 = c8 ^ ((row >> 3) & 7);
                const int rg = wrapN(v0 - 16 + row);
                const int fb = k0 + c8 * 8;
                const u16x8 a = *reinterpret_cast<const u16x8*>(A + (size_t)rg * 256 + fb);
                const float4 sc0 = *reinterpret_cast<const float4*>(ssS + fb);
                const float4 sc1 = *reinterpret_cast<const float4*>(ssS + fb + 4);
                const float4 sh0 = *reinterpret_cast<const float4*>(ssS + 256 + fb);
                const float4 sh1 = *reinterpret_cast<const float4*>(ssS + 256 + fb + 4);
                u16x8 p;
                p[0] = f2bf(fmaxf(bf2f(a[0]) * sc0.x + sh0.x, 0.f));
                p[1] = f2bf(fmaxf(bf2f(a[1]) * sc0.y + sh0.y, 0.f));
                p[2] = f2bf(fmaxf(bf2f(a[2]) * sc0.z + sh0.z, 0.f));
                p[3] = f2bf(fmaxf(bf2f(a[3]) * sc0.w + sh0.w, 0.f));
                p[4] = f2bf(fmaxf(bf2f(a[4]) * sc1.x + sh1.x, 0.f));
                p[5] = f2bf(fmaxf(bf2f(a[5]) * sc1.y + sh1.y, 0.f));
                p[6] = f2bf(fmaxf(bf2f(a[6]) * sc1.z + sh1.z, 0.f));
                p[7] = f2bf(fmaxf(bf2f(a[7]) * sc1.w + sh1.w, 0.f));
                *reinterpret_cast<u16x8*>(xr + row * 160 + pc8 * 16) = p;
            }
        }
        __syncthreads();
        if (t < 128) {   // As-build: depth-8 rolling, 16 q-groups x 8 c8
            const int q = t >> 3, c8 = t & 7;
            const int r0 = 8 * q;
            float S[8] = {};
            #pragma unroll
            for (int i = 0; i < 17; ++i) {
                const int r = r0 + i;
                const u16x8 h = *reinterpret_cast<const u16x8*>(
                    xr + r * 160 + ((c8 ^ ((r >> 3) & 7)) * 16));
                #pragma unroll
                for (int j = 0; j < 8; ++j) S[j] += bf2f(h[j]);
            }
            #pragma unroll
            for (int jr = 0; jr < 8; ++jr) {
                const int l = r0 + jr;
                u16x8 o;
                #pragma unroll
                for (int j = 0; j < 8; ++j) o[j] = f2bf(S[j] * inv17);
                *reinterpret_cast<u16x8*>(As + l * 128 + ((c8 ^ (l & 7)) * 16)) = o;
                if (jr < 7) {
                    const int ra = l + 17, rs = l;
                    const u16x8 ha = *reinterpret_cast<const u16x8*>(
                        xr + ra * 160 + ((c8 ^ ((ra >> 3) & 7)) * 16));
                    const u16x8 hs = *reinterpret_cast<const u16x8*>(
                        xr + rs * 160 + ((c8 ^ ((rs >> 3) & 7)) * 16));
                    #pragma unroll
                    for (int j = 0; j < 8; ++j) S[j] += bf2f(ha[j]) - bf2f(hs[j]);
                }
            }
        }
        __syncthreads();
        #pragma unroll
        for (int kk = 0; kk < 2; ++kk) {
            const int klog = kk * 64 + ((lane >> 4) << 4);
            bf16x8 af[2];
            #pragma unroll
            for (int mi = 0; mi < 2; ++mi) {
                const int row = wr + mi * 16 + (lane & 15);
                af[mi] = *reinterpret_cast<const bf16x8*>(As + row * 128 + (klog ^ ((row & 7) << 4)));
            }
            #pragma unroll
            for (int h = 0; h < 2; ++h)
                #pragma unroll
                for (int ni = 0; ni < 4; ++ni) {
                    const int rl = h * 128 + wcx * 64 + ni * 16 + (lane & 15);
                    const bf16x8 bv = *reinterpret_cast<const bf16x8*>(Bs + rl * 128 + (klog ^ ((rl & 7) << 4)));
                    #pragma unroll
                    for (int mi = 0; mi < 2; ++mi)
                        acc[h][mi][ni] = __builtin_amdgcn_mfma_f32_16x16x32_bf16(af[mi], bv, acc[h][mi][ni], 0, 0, 0);
                }
        }
        __syncthreads();
    }

    // epilogue: relu + per-row dots with Wl -> uL/wL in LDS (no global round-trip)
    float b2v[2][4], wav[2][4], wbv[2][4];
    #pragma unroll
    for (int h = 0; h < 2; ++h)
        #pragma unroll
        for (int ni = 0; ni < 4; ++ni) {
            const int col = h * 128 + wcx * 64 + ni * 16 + (lane & 15);
            b2v[h][ni] = b2[col];
            wav[h][ni] = Wl[col];
            wbv[h][ni] = Wl[256 + col];
        }
    float* uW = (float*)smem;            // [2][128]
    float* wW = (float*)(smem + 1024);   // [2][128]
    float* uL = (float*)(smem + 23040);         // [128]
    float* wL = (float*)(smem + 23040 + 512);   // [128]
    float* PS = (float*)(smem + 23040 + 1024);  // [112]
    #pragma unroll
    for (int mi = 0; mi < 2; ++mi)
        #pragma unroll
        for (int r = 0; r < 4; ++r) {
            float pu = 0.f, pw = 0.f;
            #pragma unroll
            for (int h = 0; h < 2; ++h)
                #pragma unroll
                for (int ni = 0; ni < 4; ++ni) {
                    const float hv = fmaxf(acc[h][mi][ni][r] + b2v[h][ni], 0.f);
                    pu += hv * wav[h][ni];
                    pw += hv * wbv[h][ni];
                }
            pu += __shfl_xor(pu, 1); pu += __shfl_xor(pu, 2);
            pu += __shfl_xor(pu, 4); pu += __shfl_xor(pu, 8);
            pw += __shfl_xor(pw, 1); pw += __shfl_xor(pw, 2);
            pw += __shfl_xor(pw, 4); pw += __shfl_xor(pw, 8);
            if ((lane & 15) == 0) {
                const int rl = wr + mi * 16 + ((lane >> 4) << 2) + r;
                uW[wcx * 128 + rl] = pu;
                wW[wcx * 128 + rl] = pw;
            }
        }
    __syncthreads();
    if (t < 128) {
        uL[t] = uW[t] + uW[128 + t];
        wL[t] = wW[t] + wW[128 + t];
    }
    __syncthreads();

    // P for nodes [v0, v0+112): PS[i] uses uL[i..i+16], wL[i+8]
    if (t < 112) {
        const int l = t + 8;
        float s = uL[l] + 16.0f * wL[l];
        #pragma unroll
        for (int o = 1; o <= 8; ++o)
            s += uL[l + o] + uL[l - o];
        PS[t] = s;
    }
    __syncthreads();

    // edge outputs for nodes [v0, v0+104)
    const float blv = bl[0];
    #pragma unroll
    for (int rr = 0; rr < 4; ++rr) {
        const int q = t + rr * 512;              // [0, 2048); valid < 1664
        if (q >= 1664) continue;
        const int half = (q >= 832) ? 1 : 0;
        const int e = q - half * 832;
        const int i = e >> 3, off = e & 7;
        const int v = v0 + i;
        if (v >= NN) continue;
        if (!half) {   // forward edge (v -> v+1+off): P[v] + w[v+1+off]
            out[v * 8 + off] = sigmoidf_((PS[i] + wL[i + 9 + off]) * inv17 + blv);
        } else {       // reverse edge owned by tt = v: P[v+1+off] + w[v]
            out[NK + v * 8 + off] = sigmoidf_((PS[i + 1 + off] + wL[i + 8]) * inv17 + blv);
        }
    }
}

// ---------------- launch ----------------
extern "C" void kernel_launch(void* const* d_in, const int* in_sizes, int n_in,
                              void* d_out, int out_size, void* d_ws, size_t ws_size,
                              hipStream_t stream)
{
    const float* x      = (const float*)d_in[0];
    const float* W1     = (const float*)d_in[1];
    const float* b1     = (const float*)d_in[2];
    const float* gamma1 = (const float*)d_in[3];
    const float* beta1  = (const float*)d_in[4];
    const float* W2     = (const float*)d_in[5];
    const float* b2     = (const float*)d_in[6];
    const float* Wl     = (const float*)d_in[7];
    const float* bl     = (const float*)d_in[8];
    float* out = (float*)d_out;

    float*    asum = (float*)d_ws;                   // [1024]
    ushort*   A    = (ushort*)(asum + 1024);         // [NN,256] bf16
    ushort*   W1t  = A + (size_t)NN * 256;           // [256,128]
    ushort*   W2t  = W1t + 256 * 128;                // [256,256]

    k_prep  <<<49,   512, 0, stream>>>(W1, W2, W1t, W2t, asum);
    k_fused1<<<NT1,  512, 0, stream>>>(x, W1t, b1, A, asum);
    k_fused2<<<NT2B, 512, 0, stream>>>(A, W2t, gamma1, beta1, b2, Wl, bl, asum, out);
}

// Round 16
// 48.694 us; speedup vs baseline: 1.1508x; 1.1508x over previous
//
#include <hip/hip_runtime.h>
#include <hip/hip_bf16.h>
#include <math.h>

#define NN    20000
#define NK    160000          // NN*8
#define NEDGE 320000
#define HID   256
#define INFEAT 128
#define EPSF  1e-5f
#define NT1   313             // 64-row tiles (fused1)
#define MOUT  104             // out-tile nodes per fused2 block
#define NT2B  193             // ceil(20000/104)

typedef __bf16  bf16x8 __attribute__((ext_vector_type(8)));
typedef float   f32x4  __attribute__((ext_vector_type(4)));
typedef ushort  u16x8  __attribute__((ext_vector_type(8)));

__device__ __forceinline__ float sigmoidf_(float x) { return 1.0f / (1.0f + expf(-x)); }

__device__ __forceinline__ ushort f2bf(float f) {
    __hip_bfloat16 h = __float2bfloat16(f);
    return __builtin_bit_cast(ushort, h);
}
__device__ __forceinline__ float bf2f(ushort u) {
    return __builtin_bit_cast(float, ((unsigned int)u) << 16);
}
__device__ __forceinline__ int wrapN(int v) {
    return (v < 0) ? v + NN : ((v >= NN) ? v - NN : v);
}

#define LDSP(p) ((__attribute__((address_space(3))) unsigned int*)(p))
#define GBLP(p) ((const __attribute__((address_space(1))) unsigned int*)(p))
#define GLD16(g, l) __builtin_amdgcn_global_load_lds(GBLP(g), LDSP(l), 16, 0, 0)

// ============ kernel 1: prep (W1t, W2t, zero asum), 49 blocks ============
__global__ __launch_bounds__(512, 2) void k_prep(const float* __restrict__ W1,
    const float* __restrict__ W2, ushort* __restrict__ W1t,
    ushort* __restrict__ W2t, float* __restrict__ asum)
{
    const int b = blockIdx.x, t = threadIdx.x;
    if (b < 16) {
        const int e = (b * 512 + t) * 4;            // W1t: 32768 elements
        ushort4 o;
        #pragma unroll
        for (int j = 0; j < 4; ++j) {
            const int ee = e + j;
            const int n = ee >> 7, k = ee & 127;    // W1t[n][k] = W1[k][n]
            ((ushort*)&o)[j] = f2bf(W1[k * 256 + n]);
        }
        *reinterpret_cast<ushort4*>(W1t + e) = o;
    } else if (b < 48) {
        const int e = ((b - 16) * 512 + t) * 4;     // W2t: 65536 elements
        ushort4 o;
        #pragma unroll
        for (int j = 0; j < 4; ++j) {
            const int ee = e + j;
            const int n = ee >> 8, k = ee & 255;    // W2t[n][k] = W2[k][n]
            ((ushort*)&o)[j] = f2bf(W2[k * 256 + n]);
        }
        *reinterpret_cast<ushort4*>(W2t + e) = o;
    } else {
        asum[t]       = 0.f;
        asum[512 + t] = 0.f;
    }
}

// ====== kernel 2: A = agg(x) @ W1 + b1 (agg fused in staging); BN partials -> asum ======
// 313 blocks x 512; tile 64(M) x 256(N), BK=64. xraw: 80 rows f32, 272B padded stride.
__global__ __launch_bounds__(512, 2) void k_fused1(const float* __restrict__ x,
    const ushort* __restrict__ W1t, const float* __restrict__ b1,
    ushort* __restrict__ A, float* __restrict__ asum)
{
    __shared__ alignas(16) char smem[21760 + 8192 + 32768];
    char* xr = smem;                    // 80 x 272B (f32, padded)
    char* As = smem + 21760;            // 64 x 128B (bf16, swizzled)
    char* Bs = smem + 21760 + 8192;     // 256 x 128B (bf16, swizzled)

    const int t = threadIdx.x;
    const int wave = t >> 6, lane = t & 63;
    const int wr = (wave >> 2) * 32;
    const int wc = (wave & 3) * 32;
    const int bm = blockIdx.x * 64;
    const float inv17 = 1.0f / 17.0f;
    f32x4 acc[2][2][2] = {};   // [ny][mi][ni]

    #pragma unroll
    for (int kt = 0; kt < 2; ++kt) {
        const int k0 = kt * 64;
        #pragma unroll
        for (int it = 0; it < 4; ++it) {   // stage B (async): 256x64 bf16, swizzled src
            const int cb = (it * 8 + wave) * 64 + lane;
            const int row = cb >> 3;
            const int lk = (cb & 7) ^ (row & 7);
            GLD16(W1t + (size_t)row * INFEAT + k0 + lk * 8, Bs + (it * 8 + wave) * 1024);
        }
        // reg-stage xraw: x rows [bm-8, bm+72) x 64 f32 cols, padded stride
        #pragma unroll
        for (int r3 = 0; r3 < 3; ++r3) {
            const int c = r3 * 512 + t;
            if (c < 1280) {
                const int row = c >> 4, cc = c & 15;
                const int rg = wrapN(bm - 8 + row);
                const float4 v = *reinterpret_cast<const float4*>(
                    x + (size_t)rg * INFEAT + k0 + cc * 4);
                *reinterpret_cast<float4*>(xr + row * 272 + cc * 16) = v;
            }
        }
        __syncthreads();
        {   // build As[row][64] = (1/17) * sum_{i=0..16} xraw[row+i]
            const int row = t >> 3, c8 = t & 7;
            float S[8] = {};
            #pragma unroll
            for (int i = 0; i < 17; ++i) {
                const float4 a = *reinterpret_cast<const float4*>(xr + (row + i) * 272 + c8 * 32);
                const float4 bq = *reinterpret_cast<const float4*>(xr + (row + i) * 272 + c8 * 32 + 16);
                S[0] += a.x;  S[1] += a.y;  S[2] += a.z;  S[3] += a.w;
                S[4] += bq.x; S[5] += bq.y; S[6] += bq.z; S[7] += bq.w;
            }
            u16x8 o;
            #pragma unroll
            for (int j = 0; j < 8; ++j) o[j] = f2bf(S[j] * inv17);
            *reinterpret_cast<u16x8*>(As + row * 128 + ((c8 ^ (row & 7)) * 16)) = o;
        }
        __syncthreads();
        #pragma unroll
        for (int kk = 0; kk < 2; ++kk) {
            const int klog = kk * 64 + ((lane >> 4) << 4);
            bf16x8 af[2];
            #pragma unroll
            for (int mi = 0; mi < 2; ++mi) {
                const int row = wr + mi * 16 + (lane & 15);
                af[mi] = *reinterpret_cast<const bf16x8*>(As + row * 128 + (klog ^ ((row & 7) << 4)));
            }
            #pragma unroll
            for (int ny = 0; ny < 2; ++ny)
                #pragma unroll
                for (int ni = 0; ni < 2; ++ni) {
                    const int row = ny * 128 + wc + ni * 16 + (lane & 15);
                    const bf16x8 bv = *reinterpret_cast<const bf16x8*>(Bs + row * 128 + (klog ^ ((row & 7) << 4)));
                    #pragma unroll
                    for (int mi = 0; mi < 2; ++mi)
                        acc[ny][mi][ni] = __builtin_amdgcn_mfma_f32_16x16x32_bf16(af[mi], bv, acc[ny][mi][ni], 0, 0, 0);
                }
        }
        __syncthreads();
    }

    // epilogue: bias, store A (bf16), BN partials -> global atomic accumulation
    float* sS  = (float*)smem;            // [8][64]
    float* s2S = (float*)(smem + 2048);   // [8][64]
    #pragma unroll
    for (int ny = 0; ny < 2; ++ny)
        #pragma unroll
        for (int ni = 0; ni < 2; ++ni) {
            const int colL = ny * 128 + wc + ni * 16 + (lane & 15);
            const float bv = b1[colL];
            float sv = 0.f, s2v = 0.f;
            #pragma unroll
            for (int mi = 0; mi < 2; ++mi)
                #pragma unroll
                for (int r = 0; r < 4; ++r) {
                    const int row = bm + wr + mi * 16 + ((lane >> 4) << 2) + r;
                    if (row < NN) {
                        const float val = acc[ny][mi][ni][r] + bv;
                        A[(size_t)row * 256 + colL] = f2bf(val);
                        sv += val; s2v += val * val;
                    }
                }
            sv  += __shfl_xor(sv, 16);  sv  += __shfl_xor(sv, 32);
            s2v += __shfl_xor(s2v, 16); s2v += __shfl_xor(s2v, 32);
            if (lane < 16) {
                sS [wave * 64 + ny * 32 + ni * 16 + lane] = sv;
                s2S[wave * 64 + ny * 32 + ni * 16 + lane] = s2v;
            }
        }
    __syncthreads();
    if (t < 256) {
        const int col = t;
        const int idx = (col >> 7) * 32 + ((col >> 4) & 1) * 16 + (col & 15);
        const int wcx = (col & 127) >> 5;
        atomicAdd(&asum[col],       sS [wcx * 64 + idx] + sS [(wcx + 4) * 64 + idx]);
        atomicAdd(&asum[512 + col], s2S[wcx * 64 + idx] + s2S[(wcx + 4) * 64 + idx]);
    }
}

// ===== kernel 3: h2 = relu( agg(relu(bn(A))) @ W2 + b2 ), dots, P, edge outputs =====
// Out-tile M=104; GEMM rows = 128 (halo recompute, circular graph => exact).
// R14 structure, single change: full Bs (256 rows) staged async, no half-split.
__global__ __launch_bounds__(512, 2) void k_fused2(const ushort* __restrict__ A,
    const ushort* __restrict__ W2t, const float* __restrict__ gamma,
    const float* __restrict__ beta, const float* __restrict__ b2,
    const float* __restrict__ Wl, const float* __restrict__ bl,
    const float* __restrict__ asum, float* __restrict__ out)
{
    __shared__ alignas(16) char smem[23040 + 16384 + 32768 + 2048];
    char* xr   = smem;                            // 144 x 160B (bf16 bnrelu'd, padded)
    char* As   = smem + 23040;                    // 128 x 128B swizzled
    char* Bs   = smem + 23040 + 16384;            // 256 x 128B swizzled (full N)
    float* ssS = (float*)(smem + 23040 + 16384 + 32768);  // sc[256] | sh[256]

    const int b = blockIdx.x, t = threadIdx.x;
    const int wave = t >> 6, lane = t & 63;
    const int wr  = (wave >> 1) * 32;       // 4 row-quads
    const int wcx = (wave & 1);             // 2 col groups of 64 within 128-half
    const int v0 = b * MOUT;
    const float inv17 = 1.0f / 17.0f;

    if (t < 256) {
        const float invn = 1.0f / (float)NN;
        const float mu  = asum[t] * invn;
        const float var = asum[512 + t] * invn - mu * mu;
        const float sc  = gamma[t] * rsqrtf(var + EPSF);
        ssS[t]       = sc;
        ssS[256 + t] = beta[t] - mu * sc;
    }
    __syncthreads();

    f32x4 acc[2][2][4] = {};   // [h][mi][ni]

    #pragma unroll
    for (int kt = 0; kt < 4; ++kt) {
        const int k0 = kt * 64;
        #pragma unroll
        for (int it = 0; it < 4; ++it) {   // stage B full (async): 256x64
            const int cb = (it * 8 + wave) * 64 + lane;
            const int row = cb >> 3;
            const int lk = (cb & 7) ^ (row & 7);
            GLD16(W2t + (size_t)row * 256 + k0 + lk * 8, Bs + (it * 8 + wave) * 1024);
        }
        // reg-stage xr = bnrelu(A rows wrapN(v0-16+row), cols [k0,k0+64)): 1152 chunks
        #pragma unroll
        for (int r3 = 0; r3 < 3; ++r3) {
            const int c = r3 * 512 + t;
            if (c < 1152) {
                const int row = c >> 3, c8 = c & 7;
                const int rg = wrapN(v0 - 16 + row);
                const int fb = k0 + c8 * 8;
                const u16x8 a = *reinterpret_cast<const u16x8*>(A + (size_t)rg * 256 + fb);
                const float4 sc0 = *reinterpret_cast<const float4*>(ssS + fb);
                const float4 sc1 = *reinterpret_cast<const float4*>(ssS + fb + 4);
                const float4 sh0 = *reinterpret_cast<const float4*>(ssS + 256 + fb);
                const float4 sh1 = *reinterpret_cast<const float4*>(ssS + 256 + fb + 4);
                u16x8 p;
                p[0] = f2bf(fmaxf(bf2f(a[0]) * sc0.x + sh0.x, 0.f));
                p[1] = f2bf(fmaxf(bf2f(a[1]) * sc0.y + sh0.y, 0.f));
                p[2] = f2bf(fmaxf(bf2f(a[2]) * sc0.z + sh0.z, 0.f));
                p[3] = f2bf(fmaxf(bf2f(a[3]) * sc0.w + sh0.w, 0.f));
                p[4] = f2bf(fmaxf(bf2f(a[4]) * sc1.x + sh1.x, 0.f));
                p[5] = f2bf(fmaxf(bf2f(a[5]) * sc1.y + sh1.y, 0.f));
                p[6] = f2bf(fmaxf(bf2f(a[6]) * sc1.z + sh1.z, 0.f));
                p[7] = f2bf(fmaxf(bf2f(a[7]) * sc1.w + sh1.w, 0.f));
                *reinterpret_cast<u16x8*>(xr + row * 160 + c8 * 16) = p;
            }
        }
        __syncthreads();

        {   // build As: 2 rows/thread, rolling 17-tap (512 threads)
            const int q = t >> 3, c8 = t & 7;
            const int r0 = 2 * q;
            float S[8] = {};
            #pragma unroll
            for (int i = 0; i < 17; ++i) {
                const u16x8 h = *reinterpret_cast<const u16x8*>(xr + (r0 + i) * 160 + c8 * 16);
                #pragma unroll
                for (int j = 0; j < 8; ++j) S[j] += bf2f(h[j]);
            }
            u16x8 o;
            #pragma unroll
            for (int j = 0; j < 8; ++j) o[j] = f2bf(S[j] * inv17);
            *reinterpret_cast<u16x8*>(As + r0 * 128 + ((c8 ^ (r0 & 7)) * 16)) = o;
            const u16x8 ha = *reinterpret_cast<const u16x8*>(xr + (r0 + 17) * 160 + c8 * 16);
            const u16x8 hs = *reinterpret_cast<const u16x8*>(xr + r0 * 160 + c8 * 16);
            #pragma unroll
            for (int j = 0; j < 8; ++j) S[j] += bf2f(ha[j]) - bf2f(hs[j]);
            const int r1 = r0 + 1;
            #pragma unroll
            for (int j = 0; j < 8; ++j) o[j] = f2bf(S[j] * inv17);
            *reinterpret_cast<u16x8*>(As + r1 * 128 + ((c8 ^ (r1 & 7)) * 16)) = o;
        }
        __syncthreads();   // As + full Bs ready

        #pragma unroll
        for (int kk = 0; kk < 2; ++kk) {
            const int klog = kk * 64 + ((lane >> 4) << 4);
            bf16x8 af[2];
            #pragma unroll
            for (int mi = 0; mi < 2; ++mi) {
                const int row = wr + mi * 16 + (lane & 15);
                af[mi] = *reinterpret_cast<const bf16x8*>(As + row * 128 + (klog ^ ((row & 7) << 4)));
            }
            #pragma unroll
            for (int h = 0; h < 2; ++h)
                #pragma unroll
                for (int ni = 0; ni < 4; ++ni) {
                    const int rl = h * 128 + wcx * 64 + ni * 16 + (lane & 15);
                    const bf16x8 bv = *reinterpret_cast<const bf16x8*>(Bs + rl * 128 + (klog ^ ((rl & 7) << 4)));
                    #pragma unroll
                    for (int mi = 0; mi < 2; ++mi)
                        acc[h][mi][ni] = __builtin_amdgcn_mfma_f32_16x16x32_bf16(af[mi], bv, acc[h][mi][ni], 0, 0, 0);
                }
        }
        __syncthreads();   // end kt
    }

    // epilogue: relu + per-row dots with Wl -> uL/wL in LDS (no global round-trip)
    float b2v[2][4], wav[2][4], wbv[2][4];
    #pragma unroll
    for (int h = 0; h < 2; ++h)
        #pragma unroll
        for (int ni = 0; ni < 4; ++ni) {
            const int col = h * 128 + wcx * 64 + ni * 16 + (lane & 15);
            b2v[h][ni] = b2[col];
            wav[h][ni] = Wl[col];
            wbv[h][ni] = Wl[256 + col];
        }
    float* uW = (float*)smem;            // [2][128]
    float* wW = (float*)(smem + 1024);   // [2][128]
    float* uL = (float*)(smem + 23040);         // [128]
    float* wL = (float*)(smem + 23040 + 512);   // [128]
    float* PS = (float*)(smem + 23040 + 1024);  // [112]
    #pragma unroll
    for (int mi = 0; mi < 2; ++mi)
        #pragma unroll
        for (int r = 0; r < 4; ++r) {
            float pu = 0.f, pw = 0.f;
            #pragma unroll
            for (int h = 0; h < 2; ++h)
                #pragma unroll
                for (int ni = 0; ni < 4; ++ni) {
                    const float hv = fmaxf(acc[h][mi][ni][r] + b2v[h][ni], 0.f);
                    pu += hv * wav[h][ni];
                    pw += hv * wbv[h][ni];
                }
            pu += __shfl_xor(pu, 1); pu += __shfl_xor(pu, 2);
            pu += __shfl_xor(pu, 4); pu += __shfl_xor(pu, 8);
            pw += __shfl_xor(pw, 1); pw += __shfl_xor(pw, 2);
            pw += __shfl_xor(pw, 4); pw += __shfl_xor(pw, 8);
            if ((lane & 15) == 0) {
                const int rl = wr + mi * 16 + ((lane >> 4) << 2) + r;
                uW[wcx * 128 + rl] = pu;
                wW[wcx * 128 + rl] = pw;
            }
        }
    __syncthreads();
    if (t < 128) {
        uL[t] = uW[t] + uW[128 + t];
        wL[t] = wW[t] + wW[128 + t];
    }
    __syncthreads();

    // P for nodes [v0, v0+112): PS[i] uses uL[i..i+16], wL[i+8]
    if (t < 112) {
        const int l = t + 8;
        float s = uL[l] + 16.0f * wL[l];
        #pragma unroll
        for (int o = 1; o <= 8; ++o)
            s += uL[l + o] + uL[l - o];
        PS[t] = s;
    }
    __syncthreads();

    // edge outputs for nodes [v0, v0+104)
    const float blv = bl[0];
    #pragma unroll
    for (int rr = 0; rr < 4; ++rr) {
        const int q = t + rr * 512;              // [0, 2048); valid < 1664
        if (q >= 1664) continue;
        const int half = (q >= 832) ? 1 : 0;
        const int e = q - half * 832;
        const int i = e >> 3, off = e & 7;
        const int v = v0 + i;
        if (v >= NN) continue;
        if (!half) {   // forward edge (v -> v+1+off): P[v] + w[v+1+off]
            out[v * 8 + off] = sigmoidf_((PS[i] + wL[i + 9 + off]) * inv17 + blv);
        } else {       // reverse edge owned by tt = v: P[v+1+off] + w[v]
            out[NK + v * 8 + off] = sigmoidf_((PS[i + 1 + off] + wL[i + 8]) * inv17 + blv);
        }
    }
}

// ---------------- launch ----------------
extern "C" void kernel_launch(void* const* d_in, const int* in_sizes, int n_in,
                              void* d_out, int out_size, void* d_ws, size_t ws_size,
                              hipStream_t stream)
{
    const float* x      = (const float*)d_in[0];
    const float* W1     = (const float*)d_in[1];
    const float* b1     = (const float*)d_in[2];
    const float* gamma1 = (const float*)d_in[3];
    const float* beta1  = (const float*)d_in[4];
    const float* W2     = (const float*)d_in[5];
    const float* b2     = (const float*)d_in[6];
    const float* Wl     = (const float*)d_in[7];
    const float* bl     = (const float*)d_in[8];
    float* out = (float*)d_out;

    float*    asum = (float*)d_ws;                   // [1024]
    ushort*   A    = (ushort*)(asum + 1024);         // [NN,256] bf16
    ushort*   W1t  = A + (size_t)NN * 256;           // [256,128]
    ushort*   W2t  = W1t + 256 * 128;                // [256,256]

    k_prep  <<<49,   512, 0, stream>>>(W1, W2, W1t, W2t, asum);
    k_fused1<<<NT1,  512, 0, stream>>>(x, W1t, b1, A, asum);
    k_fused2<<<NT2B, 512, 0, stream>>>(A, W2t, gamma1, beta1, b2, Wl, bl, asum, out);
}

// Round 17
// 45.354 us; speedup vs baseline: 1.2356x; 1.0736x over previous
//
#include <hip/hip_runtime.h>
#include <hip/hip_bf16.h>
#include <math.h>

#define NN    20000
#define NK    160000          // NN*8
#define NEDGE 320000
#define HID   256
#define INFEAT 128
#define EPSF  1e-5f
#define NT1   313             // 64-row tiles (fused1)
#define MOUT  104             // out-tile nodes per fused2 block
#define NT2B  193             // ceil(20000/104)

typedef __bf16  bf16x8 __attribute__((ext_vector_type(8)));
typedef float   f32x4  __attribute__((ext_vector_type(4)));
typedef ushort  u16x8  __attribute__((ext_vector_type(8)));

__device__ __forceinline__ float sigmoidf_(float x) { return 1.0f / (1.0f + expf(-x)); }

__device__ __forceinline__ ushort f2bf(float f) {
    __hip_bfloat16 h = __float2bfloat16(f);
    return __builtin_bit_cast(ushort, h);
}
__device__ __forceinline__ float bf2f(ushort u) {
    return __builtin_bit_cast(float, ((unsigned int)u) << 16);
}
__device__ __forceinline__ int wrapN(int v) {
    return (v < 0) ? v + NN : ((v >= NN) ? v - NN : v);
}

#define LDSP(p) ((__attribute__((address_space(3))) unsigned int*)(p))
#define GBLP(p) ((const __attribute__((address_space(1))) unsigned int*)(p))
#define GLD16(g, l) __builtin_amdgcn_global_load_lds(GBLP(g), LDSP(l), 16, 0, 0)

__device__ __forceinline__ u16x8 bnrelu8(const u16x8 a, const float* ssS, int fb) {
    const float4 sc0 = *reinterpret_cast<const float4*>(ssS + fb);
    const float4 sc1 = *reinterpret_cast<const float4*>(ssS + fb + 4);
    const float4 sh0 = *reinterpret_cast<const float4*>(ssS + 256 + fb);
    const float4 sh1 = *reinterpret_cast<const float4*>(ssS + 256 + fb + 4);
    u16x8 p;
    p[0] = f2bf(fmaxf(bf2f(a[0]) * sc0.x + sh0.x, 0.f));
    p[1] = f2bf(fmaxf(bf2f(a[1]) * sc0.y + sh0.y, 0.f));
    p[2] = f2bf(fmaxf(bf2f(a[2]) * sc0.z + sh0.z, 0.f));
    p[3] = f2bf(fmaxf(bf2f(a[3]) * sc0.w + sh0.w, 0.f));
    p[4] = f2bf(fmaxf(bf2f(a[4]) * sc1.x + sh1.x, 0.f));
    p[5] = f2bf(fmaxf(bf2f(a[5]) * sc1.y + sh1.y, 0.f));
    p[6] = f2bf(fmaxf(bf2f(a[6]) * sc1.z + sh1.z, 0.f));
    p[7] = f2bf(fmaxf(bf2f(a[7]) * sc1.w + sh1.w, 0.f));
    return p;
}

// ============ kernel 1: prep (W1t, W2t, zero asum), 49 blocks ============
__global__ __launch_bounds__(512, 2) void k_prep(const float* __restrict__ W1,
    const float* __restrict__ W2, ushort* __restrict__ W1t,
    ushort* __restrict__ W2t, float* __restrict__ asum)
{
    const int b = blockIdx.x, t = threadIdx.x;
    if (b < 16) {
        const int e = (b * 512 + t) * 4;            // W1t: 32768 elements
        ushort4 o;
        #pragma unroll
        for (int j = 0; j < 4; ++j) {
            const int ee = e + j;
            const int n = ee >> 7, k = ee & 127;    // W1t[n][k] = W1[k][n]
            ((ushort*)&o)[j] = f2bf(W1[k * 256 + n]);
        }
        *reinterpret_cast<ushort4*>(W1t + e) = o;
    } else if (b < 48) {
        const int e = ((b - 16) * 512 + t) * 4;     // W2t: 65536 elements
        ushort4 o;
        #pragma unroll
        for (int j = 0; j < 4; ++j) {
            const int ee = e + j;
            const int n = ee >> 8, k = ee & 255;    // W2t[n][k] = W2[k][n]
            ((ushort*)&o)[j] = f2bf(W2[k * 256 + n]);
        }
        *reinterpret_cast<ushort4*>(W2t + e) = o;
    } else {
        asum[t]       = 0.f;
        asum[512 + t] = 0.f;
    }
}

// ====== kernel 2: A = agg(x) @ W1 + b1 (agg fused in staging); BN partials -> asum ======
// 313 blocks x 512; tile 64(M) x 256(N), BK=64. xraw: 80 rows f32, 272B padded stride.
// T14: x reg-loads for kt+1 issued under MFMA(kt); B GLD16 drains under As-build.
__global__ __launch_bounds__(512, 2) void k_fused1(const float* __restrict__ x,
    const ushort* __restrict__ W1t, const float* __restrict__ b1,
    ushort* __restrict__ A, float* __restrict__ asum)
{
    __shared__ alignas(16) char smem[21760 + 8192 + 32768];
    char* xr = smem;                    // 80 x 272B (f32, padded)
    char* As = smem + 21760;            // 64 x 128B (bf16, swizzled)
    char* Bs = smem + 21760 + 8192;     // 256 x 128B (bf16, swizzled)

    const int t = threadIdx.x;
    const int wave = t >> 6, lane = t & 63;
    const int wr = (wave >> 2) * 32;
    const int wc = (wave & 3) * 32;
    const int bm = blockIdx.x * 64;
    const float inv17 = 1.0f / 17.0f;
    f32x4 acc[2][2][2] = {};   // [ny][mi][ni]

    // chunk mapping: c = r3*512 + t; row = c>>4, cc = c&15 (c < 1280)
    const int rw0 = wrapN(bm - 8 + (t >> 4)),          cc0 = t & 15;
    const int rw1 = wrapN(bm - 8 + ((512 + t) >> 4)),  cc1 = (512 + t) & 15;
    const int rw2 = wrapN(bm - 8 + ((1024 + t) >> 4)), cc2 = (1024 + t) & 15;
    const bool v2 = (1024 + t) < 1280;

    // prologue: load x chunks for kt=0
    float4 xq0 = *reinterpret_cast<const float4*>(x + (size_t)rw0 * INFEAT + cc0 * 4);
    float4 xq1 = *reinterpret_cast<const float4*>(x + (size_t)rw1 * INFEAT + cc1 * 4);
    float4 xq2 = v2 ? *reinterpret_cast<const float4*>(x + (size_t)rw2 * INFEAT + cc2 * 4)
                    : make_float4(0.f, 0.f, 0.f, 0.f);

    #pragma unroll
    for (int kt = 0; kt < 2; ++kt) {
        const int k0 = kt * 64;
        // write staged x -> xr
        *reinterpret_cast<float4*>(xr + (t >> 4) * 272 + cc0 * 16) = xq0;
        *reinterpret_cast<float4*>(xr + ((512 + t) >> 4) * 272 + cc1 * 16) = xq1;
        if (v2)
            *reinterpret_cast<float4*>(xr + ((1024 + t) >> 4) * 272 + cc2 * 16) = xq2;
        __syncthreads();
        #pragma unroll
        for (int it = 0; it < 4; ++it) {   // stage B(kt) — drain hidden under As-build
            const int cb = (it * 8 + wave) * 64 + lane;
            const int row = cb >> 3;
            const int lk = (cb & 7) ^ (row & 7);
            GLD16(W1t + (size_t)row * INFEAT + k0 + lk * 8, Bs + (it * 8 + wave) * 1024);
        }
        {   // build As[row][64] = (1/17) * sum_{i=0..16} xraw[row+i]
            const int row = t >> 3, c8 = t & 7;
            float S[8] = {};
            #pragma unroll
            for (int i = 0; i < 17; ++i) {
                const float4 a = *reinterpret_cast<const float4*>(xr + (row + i) * 272 + c8 * 32);
                const float4 bq = *reinterpret_cast<const float4*>(xr + (row + i) * 272 + c8 * 32 + 16);
                S[0] += a.x;  S[1] += a.y;  S[2] += a.z;  S[3] += a.w;
                S[4] += bq.x; S[5] += bq.y; S[6] += bq.z; S[7] += bq.w;
            }
            u16x8 o;
            #pragma unroll
            for (int j = 0; j < 8; ++j) o[j] = f2bf(S[j] * inv17);
            *reinterpret_cast<u16x8*>(As + row * 128 + ((c8 ^ (row & 7)) * 16)) = o;
        }
        __syncthreads();
        if (kt == 0) {   // issue x loads for kt=1 (hidden under MFMA, drained at sync 3)
            xq0 = *reinterpret_cast<const float4*>(x + (size_t)rw0 * INFEAT + 64 + cc0 * 4);
            xq1 = *reinterpret_cast<const float4*>(x + (size_t)rw1 * INFEAT + 64 + cc1 * 4);
            if (v2)
                xq2 = *reinterpret_cast<const float4*>(x + (size_t)rw2 * INFEAT + 64 + cc2 * 4);
        }
        #pragma unroll
        for (int kk = 0; kk < 2; ++kk) {
            const int klog = kk * 64 + ((lane >> 4) << 4);
            bf16x8 af[2];
            #pragma unroll
            for (int mi = 0; mi < 2; ++mi) {
                const int row = wr + mi * 16 + (lane & 15);
                af[mi] = *reinterpret_cast<const bf16x8*>(As + row * 128 + (klog ^ ((row & 7) << 4)));
            }
            #pragma unroll
            for (int ny = 0; ny < 2; ++ny)
                #pragma unroll
                for (int ni = 0; ni < 2; ++ni) {
                    const int row = ny * 128 + wc + ni * 16 + (lane & 15);
                    const bf16x8 bv = *reinterpret_cast<const bf16x8*>(Bs + row * 128 + (klog ^ ((row & 7) << 4)));
                    #pragma unroll
                    for (int mi = 0; mi < 2; ++mi)
                        acc[ny][mi][ni] = __builtin_amdgcn_mfma_f32_16x16x32_bf16(af[mi], bv, acc[ny][mi][ni], 0, 0, 0);
                }
        }
        __syncthreads();
    }

    // epilogue: bias, store A (bf16), BN partials -> global atomic accumulation
    float* sS  = (float*)smem;            // [8][64]
    float* s2S = (float*)(smem + 2048);   // [8][64]
    #pragma unroll
    for (int ny = 0; ny < 2; ++ny)
        #pragma unroll
        for (int ni = 0; ni < 2; ++ni) {
            const int colL = ny * 128 + wc + ni * 16 + (lane & 15);
            const float bv = b1[colL];
            float sv = 0.f, s2v = 0.f;
            #pragma unroll
            for (int mi = 0; mi < 2; ++mi)
                #pragma unroll
                for (int r = 0; r < 4; ++r) {
                    const int row = bm + wr + mi * 16 + ((lane >> 4) << 2) + r;
                    if (row < NN) {
                        const float val = acc[ny][mi][ni][r] + bv;
                        A[(size_t)row * 256 + colL] = f2bf(val);
                        sv += val; s2v += val * val;
                    }
                }
            sv  += __shfl_xor(sv, 16);  sv  += __shfl_xor(sv, 32);
            s2v += __shfl_xor(s2v, 16); s2v += __shfl_xor(s2v, 32);
            if (lane < 16) {
                sS [wave * 64 + ny * 32 + ni * 16 + lane] = sv;
                s2S[wave * 64 + ny * 32 + ni * 16 + lane] = s2v;
            }
        }
    __syncthreads();
    if (t < 256) {
        const int col = t;
        const int idx = (col >> 7) * 32 + ((col >> 4) & 1) * 16 + (col & 15);
        const int wcx = (col & 127) >> 5;
        atomicAdd(&asum[col],       sS [wcx * 64 + idx] + sS [(wcx + 4) * 64 + idx]);
        atomicAdd(&asum[512 + col], s2S[wcx * 64 + idx] + s2S[(wcx + 4) * 64 + idx]);
    }
}

// ===== kernel 3: h2 = relu( agg(relu(bn(A))) @ W2 + b2 ), dots, P, edge outputs =====
// Out-tile M=104; GEMM rows = 128 (halo recompute). Full Bs.
// T14: A reg-loads for kt+1 issued under MFMA(kt); B GLD16 drains under As-build.
__global__ __launch_bounds__(512, 2) void k_fused2(const ushort* __restrict__ A,
    const ushort* __restrict__ W2t, const float* __restrict__ gamma,
    const float* __restrict__ beta, const float* __restrict__ b2,
    const float* __restrict__ Wl, const float* __restrict__ bl,
    const float* __restrict__ asum, float* __restrict__ out)
{
    __shared__ alignas(16) char smem[23040 + 16384 + 32768 + 2048];
    char* xr   = smem;                            // 144 x 160B (bf16 bnrelu'd, padded)
    char* As   = smem + 23040;                    // 128 x 128B swizzled
    char* Bs   = smem + 23040 + 16384;            // 256 x 128B swizzled (full N)
    float* ssS = (float*)(smem + 23040 + 16384 + 32768);  // sc[256] | sh[256]

    const int b = blockIdx.x, t = threadIdx.x;
    const int wave = t >> 6, lane = t & 63;
    const int wr  = (wave >> 1) * 32;       // 4 row-quads
    const int wcx = (wave & 1);             // 2 col groups of 64 within 128-half
    const int v0 = b * MOUT;
    const float inv17 = 1.0f / 17.0f;

    if (t < 256) {
        const float invn = 1.0f / (float)NN;
        const float mu  = asum[t] * invn;
        const float var = asum[512 + t] * invn - mu * mu;
        const float sc  = gamma[t] * rsqrtf(var + EPSF);
        ssS[t]       = sc;
        ssS[256 + t] = beta[t] - mu * sc;
    }
    __syncthreads();

    f32x4 acc[2][2][4] = {};   // [h][mi][ni]

    // chunk mapping: c = r3*512 + t; row = c>>3, c8 = c&7 (c < 1152)
    const int rg0 = wrapN(v0 - 16 + (t >> 3)),          f80 = (t & 7) * 8;
    const int rg1 = wrapN(v0 - 16 + ((512 + t) >> 3)),  f81 = ((512 + t) & 7) * 8;
    const int rg2 = wrapN(v0 - 16 + ((1024 + t) >> 3)), f82 = ((1024 + t) & 7) * 8;
    const bool v2 = (1024 + t) < 1152;

    // prologue: load A chunks for kt=0
    u16x8 aq0 = *reinterpret_cast<const u16x8*>(A + (size_t)rg0 * 256 + f80);
    u16x8 aq1 = *reinterpret_cast<const u16x8*>(A + (size_t)rg1 * 256 + f81);
    u16x8 aq2 = v2 ? *reinterpret_cast<const u16x8*>(A + (size_t)rg2 * 256 + f82)
                   : u16x8{};

    #pragma unroll
    for (int kt = 0; kt < 4; ++kt) {
        const int k0 = kt * 64;
        // bnrelu + write staged A -> xr
        *reinterpret_cast<u16x8*>(xr + (t >> 3) * 160 + (t & 7) * 16)
            = bnrelu8(aq0, ssS, k0 + f80);
        *reinterpret_cast<u16x8*>(xr + ((512 + t) >> 3) * 160 + ((512 + t) & 7) * 16)
            = bnrelu8(aq1, ssS, k0 + f81);
        if (v2)
            *reinterpret_cast<u16x8*>(xr + ((1024 + t) >> 3) * 160 + ((1024 + t) & 7) * 16)
                = bnrelu8(aq2, ssS, k0 + f82);
        __syncthreads();
        #pragma unroll
        for (int it = 0; it < 4; ++it) {   // stage B(kt) — drain hidden under As-build
            const int cb = (it * 8 + wave) * 64 + lane;
            const int row = cb >> 3;
            const int lk = (cb & 7) ^ (row & 7);
            GLD16(W2t + (size_t)row * 256 + k0 + lk * 8, Bs + (it * 8 + wave) * 1024);
        }
        {   // build As: 2 rows/thread, rolling 17-tap (512 threads)
            const int q = t >> 3, c8 = t & 7;
            const int r0 = 2 * q;
            float S[8] = {};
            #pragma unroll
            for (int i = 0; i < 17; ++i) {
                const u16x8 h = *reinterpret_cast<const u16x8*>(xr + (r0 + i) * 160 + c8 * 16);
                #pragma unroll
                for (int j = 0; j < 8; ++j) S[j] += bf2f(h[j]);
            }
            u16x8 o;
            #pragma unroll
            for (int j = 0; j < 8; ++j) o[j] = f2bf(S[j] * inv17);
            *reinterpret_cast<u16x8*>(As + r0 * 128 + ((c8 ^ (r0 & 7)) * 16)) = o;
            const u16x8 ha = *reinterpret_cast<const u16x8*>(xr + (r0 + 17) * 160 + c8 * 16);
            const u16x8 hs = *reinterpret_cast<const u16x8*>(xr + r0 * 160 + c8 * 16);
            #pragma unroll
            for (int j = 0; j < 8; ++j) S[j] += bf2f(ha[j]) - bf2f(hs[j]);
            const int r1 = r0 + 1;
            #pragma unroll
            for (int j = 0; j < 8; ++j) o[j] = f2bf(S[j] * inv17);
            *reinterpret_cast<u16x8*>(As + r1 * 128 + ((c8 ^ (r1 & 7)) * 16)) = o;
        }
        __syncthreads();   // As + full Bs ready
        if (kt < 3) {      // issue A loads for kt+1 (hidden under MFMA)
            const int k1 = k0 + 64;
            aq0 = *reinterpret_cast<const u16x8*>(A + (size_t)rg0 * 256 + k1 + f80);
            aq1 = *reinterpret_cast<const u16x8*>(A + (size_t)rg1 * 256 + k1 + f81);
            if (v2)
                aq2 = *reinterpret_cast<const u16x8*>(A + (size_t)rg2 * 256 + k1 + f82);
        }
        #pragma unroll
        for (int kk = 0; kk < 2; ++kk) {
            const int klog = kk * 64 + ((lane >> 4) << 4);
            bf16x8 af[2];
            #pragma unroll
            for (int mi = 0; mi < 2; ++mi) {
                const int row = wr + mi * 16 + (lane & 15);
                af[mi] = *reinterpret_cast<const bf16x8*>(As + row * 128 + (klog ^ ((row & 7) << 4)));
            }
            #pragma unroll
            for (int h = 0; h < 2; ++h)
                #pragma unroll
                for (int ni = 0; ni < 4; ++ni) {
                    const int rl = h * 128 + wcx * 64 + ni * 16 + (lane & 15);
                    const bf16x8 bv = *reinterpret_cast<const bf16x8*>(Bs + rl * 128 + (klog ^ ((rl & 7) << 4)));
                    #pragma unroll
                    for (int mi = 0; mi < 2; ++mi)
                        acc[h][mi][ni] = __builtin_amdgcn_mfma_f32_16x16x32_bf16(af[mi], bv, acc[h][mi][ni], 0, 0, 0);
                }
        }
        __syncthreads();   // end kt
    }

    // epilogue: relu + per-row dots with Wl -> uL/wL in LDS (no global round-trip)
    float b2v[2][4], wav[2][4], wbv[2][4];
    #pragma unroll
    for (int h = 0; h < 2; ++h)
        #pragma unroll
        for (int ni = 0; ni < 4; ++ni) {
            const int col = h * 128 + wcx * 64 + ni * 16 + (lane & 15);
            b2v[h][ni] = b2[col];
            wav[h][ni] = Wl[col];
            wbv[h][ni] = Wl[256 + col];
        }
    float* uW = (float*)smem;            // [2][128]
    float* wW = (float*)(smem + 1024);   // [2][128]
    float* uL = (float*)(smem + 23040);         // [128]
    float* wL = (float*)(smem + 23040 + 512);   // [128]
    float* PS = (float*)(smem + 23040 + 1024);  // [112]
    #pragma unroll
    for (int mi = 0; mi < 2; ++mi)
        #pragma unroll
        for (int r = 0; r < 4; ++r) {
            float pu = 0.f, pw = 0.f;
            #pragma unroll
            for (int h = 0; h < 2; ++h)
                #pragma unroll
                for (int ni = 0; ni < 4; ++ni) {
                    const float hv = fmaxf(acc[h][mi][ni][r] + b2v[h][ni], 0.f);
                    pu += hv * wav[h][ni];
                    pw += hv * wbv[h][ni];
                }
            pu += __shfl_xor(pu, 1); pu += __shfl_xor(pu, 2);
            pu += __shfl_xor(pu, 4); pu += __shfl_xor(pu, 8);
            pw += __shfl_xor(pw, 1); pw += __shfl_xor(pw, 2);
            pw += __shfl_xor(pw, 4); pw += __shfl_xor(pw, 8);
            if ((lane & 15) == 0) {
                const int rl = wr + mi * 16 + ((lane >> 4) << 2) + r;
                uW[wcx * 128 + rl] = pu;
                wW[wcx * 128 + rl] = pw;
            }
        }
    __syncthreads();
    if (t < 128) {
        uL[t] = uW[t] + uW[128 + t];
        wL[t] = wW[t] + wW[128 + t];
    }
    __syncthreads();

    // P for nodes [v0, v0+112): PS[i] uses uL[i..i+16], wL[i+8]
    if (t < 112) {
        const int l = t + 8;
        float s = uL[l] + 16.0f * wL[l];
        #pragma unroll
        for (int o = 1; o <= 8; ++o)
            s += uL[l + o] + uL[l - o];
        PS[t] = s;
    }
    __syncthreads();

    // edge outputs for nodes [v0, v0+104)
    const float blv = bl[0];
    #pragma unroll
    for (int rr = 0; rr < 4; ++rr) {
        const int q = t + rr * 512;              // [0, 2048); valid < 1664
        if (q >= 1664) continue;
        const int half = (q >= 832) ? 1 : 0;
        const int e = q - half * 832;
        const int i = e >> 3, off = e & 7;
        const int v = v0 + i;
        if (v >= NN) continue;
        if (!half) {   // forward edge (v -> v+1+off): P[v] + w[v+1+off]
            out[v * 8 + off] = sigmoidf_((PS[i] + wL[i + 9 + off]) * inv17 + blv);
        } else {       // reverse edge owned by tt = v: P[v+1+off] + w[v]
            out[NK + v * 8 + off] = sigmoidf_((PS[i + 1 + off] + wL[i + 8]) * inv17 + blv);
        }
    }
}

// ---------------- launch ----------------
extern "C" void kernel_launch(void* const* d_in, const int* in_sizes, int n_in,
                              void* d_out, int out_size, void* d_ws, size_t ws_size,
                              hipStream_t stream)
{
    const float* x      = (const float*)d_in[0];
    const float* W1     = (const float*)d_in[1];
    const float* b1     = (const float*)d_in[2];
    const float* gamma1 = (const float*)d_in[3];
    const float* beta1  = (const float*)d_in[4];
    const float* W2     = (const float*)d_in[5];
    const float* b2     = (const float*)d_in[6];
    const float* Wl     = (const float*)d_in[7];
    const float* bl     = (const float*)d_in[8];
    float* out = (float*)d_out;

    float*    asum = (float*)d_ws;                   // [1024]
    ushort*   A    = (ushort*)(asum + 1024);         // [NN,256] bf16
    ushort*   W1t  = A + (size_t)NN * 256;           // [256,128]
    ushort*   W2t  = W1t + 256 * 128;                // [256,256]

    k_prep  <<<49,   512, 0, stream>>>(W1, W2, W1t, W2t, asum);
    k_fused1<<<NT1,  512, 0, stream>>>(x, W1t, b1, A, asum);
    k_fused2<<<NT2B, 512, 0, stream>>>(A, W2t, gamma1, beta1, b2, Wl, bl, asum, out);
}

// Round 18
// 44.781 us; speedup vs baseline: 1.2514x; 1.0128x over previous
//
#include <hip/hip_runtime.h>
#include <hip/hip_bf16.h>
#include <math.h>

#define NN    20000
#define NK    160000          // NN*8
#define NEDGE 320000
#define HID   256
#define INFEAT 128
#define EPSF  1e-5f
#define NT1   313             // 64-row tiles (fused1)
#define MOUT  104             // out-tile nodes per fused2 block
#define NT2B  193             // ceil(20000/104)

typedef __bf16  bf16x8 __attribute__((ext_vector_type(8)));
typedef float   f32x4  __attribute__((ext_vector_type(4)));
typedef ushort  u16x8  __attribute__((ext_vector_type(8)));

__device__ __forceinline__ float sigmoidf_(float x) { return 1.0f / (1.0f + expf(-x)); }

__device__ __forceinline__ ushort f2bf(float f) {
    __hip_bfloat16 h = __float2bfloat16(f);
    return __builtin_bit_cast(ushort, h);
}
__device__ __forceinline__ float bf2f(ushort u) {
    return __builtin_bit_cast(float, ((unsigned int)u) << 16);
}
__device__ __forceinline__ int wrapN(int v) {
    return (v < 0) ? v + NN : ((v >= NN) ? v - NN : v);
}

#define LDSP(p) ((__attribute__((address_space(3))) unsigned int*)(p))
#define GBLP(p) ((const __attribute__((address_space(1))) unsigned int*)(p))
#define GLD16(g, l) __builtin_amdgcn_global_load_lds(GBLP(g), LDSP(l), 16, 0, 0)

__device__ __forceinline__ u16x8 bnrelu8(const u16x8 a, const float* ssS, int fb) {
    const float4 sc0 = *reinterpret_cast<const float4*>(ssS + fb);
    const float4 sc1 = *reinterpret_cast<const float4*>(ssS + fb + 4);
    const float4 sh0 = *reinterpret_cast<const float4*>(ssS + 256 + fb);
    const float4 sh1 = *reinterpret_cast<const float4*>(ssS + 256 + fb + 4);
    u16x8 p;
    p[0] = f2bf(fmaxf(bf2f(a[0]) * sc0.x + sh0.x, 0.f));
    p[1] = f2bf(fmaxf(bf2f(a[1]) * sc0.y + sh0.y, 0.f));
    p[2] = f2bf(fmaxf(bf2f(a[2]) * sc0.z + sh0.z, 0.f));
    p[3] = f2bf(fmaxf(bf2f(a[3]) * sc0.w + sh0.w, 0.f));
    p[4] = f2bf(fmaxf(bf2f(a[4]) * sc1.x + sh1.x, 0.f));
    p[5] = f2bf(fmaxf(bf2f(a[5]) * sc1.y + sh1.y, 0.f));
    p[6] = f2bf(fmaxf(bf2f(a[6]) * sc1.z + sh1.z, 0.f));
    p[7] = f2bf(fmaxf(bf2f(a[7]) * sc1.w + sh1.w, 0.f));
    return p;
}

__device__ __forceinline__ u16x8 pack8(const float4 a, const float4 b) {
    u16x8 p;
    p[0] = f2bf(a.x); p[1] = f2bf(a.y); p[2] = f2bf(a.z); p[3] = f2bf(a.w);
    p[4] = f2bf(b.x); p[5] = f2bf(b.y); p[6] = f2bf(b.z); p[7] = f2bf(b.w);
    return p;
}

// ============ kernel 1: prep (W1t, W2t, zero asum), 49 blocks ============
__global__ __launch_bounds__(512, 2) void k_prep(const float* __restrict__ W1,
    const float* __restrict__ W2, ushort* __restrict__ W1t,
    ushort* __restrict__ W2t, float* __restrict__ asum)
{
    const int b = blockIdx.x, t = threadIdx.x;
    if (b < 16) {
        const int e = (b * 512 + t) * 4;            // W1t: 32768 elements
        ushort4 o;
        #pragma unroll
        for (int j = 0; j < 4; ++j) {
            const int ee = e + j;
            const int n = ee >> 7, k = ee & 127;    // W1t[n][k] = W1[k][n]
            ((ushort*)&o)[j] = f2bf(W1[k * 256 + n]);
        }
        *reinterpret_cast<ushort4*>(W1t + e) = o;
    } else if (b < 48) {
        const int e = ((b - 16) * 512 + t) * 4;     // W2t: 65536 elements
        ushort4 o;
        #pragma unroll
        for (int j = 0; j < 4; ++j) {
            const int ee = e + j;
            const int n = ee >> 8, k = ee & 255;    // W2t[n][k] = W2[k][n]
            ((ushort*)&o)[j] = f2bf(W2[k * 256 + n]);
        }
        *reinterpret_cast<ushort4*>(W2t + e) = o;
    } else {
        asum[t]       = 0.f;
        asum[512 + t] = 0.f;
    }
}

// ====== kernel 2: A = agg(x) @ W1 + b1 (agg fused in staging); BN partials -> asum ======
// 313 blocks x 512; tile 64(M) x 256(N), BK=64. xr: 80 rows bf16, 160B padded stride.
// T14: x reg-loads for kt+1 under MFMA(kt); B GLD16 drains under As-build.
// 2 barriers per kt (trailing barrier proven redundant).
__global__ __launch_bounds__(512, 2) void k_fused1(const float* __restrict__ x,
    const ushort* __restrict__ W1t, const float* __restrict__ b1,
    ushort* __restrict__ A, float* __restrict__ asum)
{
    __shared__ alignas(16) char smem[12800 + 8192 + 32768];
    char* xr = smem;                    // 80 x 160B (bf16, padded)
    char* As = smem + 12800;            // 64 x 128B (bf16, swizzled)
    char* Bs = smem + 12800 + 8192;     // 256 x 128B (bf16, swizzled)

    const int t = threadIdx.x;
    const int wave = t >> 6, lane = t & 63;
    const int wr = (wave >> 2) * 32;
    const int wc = (wave & 3) * 32;
    const int bm = blockIdx.x * 64;
    const float inv17 = 1.0f / 17.0f;
    f32x4 acc[2][2][2] = {};   // [ny][mi][ni]

    // chunk mapping: c = t (all) and c = 512+t (t<128); row = c>>3, c8 = c&7
    const int rwA = wrapN(bm - 8 + (t >> 3)),         c8A = t & 7;
    const int rwB = wrapN(bm - 8 + ((512 + t) >> 3)), c8B = (512 + t) & 7;
    const bool vB = t < 128;

    // prologue: load x chunks for kt=0 (2 float4 per chunk)
    float4 xa0 = *reinterpret_cast<const float4*>(x + (size_t)rwA * INFEAT + c8A * 8);
    float4 xa1 = *reinterpret_cast<const float4*>(x + (size_t)rwA * INFEAT + c8A * 8 + 4);
    float4 xb0 = vB ? *reinterpret_cast<const float4*>(x + (size_t)rwB * INFEAT + c8B * 8)
                    : make_float4(0.f, 0.f, 0.f, 0.f);
    float4 xb1 = vB ? *reinterpret_cast<const float4*>(x + (size_t)rwB * INFEAT + c8B * 8 + 4)
                    : make_float4(0.f, 0.f, 0.f, 0.f);

    #pragma unroll
    for (int kt = 0; kt < 2; ++kt) {
        const int k0 = kt * 64;
        // write staged x -> xr (bf16)
        *reinterpret_cast<u16x8*>(xr + (t >> 3) * 160 + c8A * 16) = pack8(xa0, xa1);
        if (vB)
            *reinterpret_cast<u16x8*>(xr + ((512 + t) >> 3) * 160 + c8B * 16) = pack8(xb0, xb1);
        __syncthreads();
        #pragma unroll
        for (int it = 0; it < 4; ++it) {   // stage B(kt) — drain hidden under As-build
            const int cb = (it * 8 + wave) * 64 + lane;
            const int row = cb >> 3;
            const int lk = (cb & 7) ^ (row & 7);
            GLD16(W1t + (size_t)row * INFEAT + k0 + lk * 8, Bs + (it * 8 + wave) * 1024);
        }
        {   // build As[row][64] = (1/17) * sum_{i=0..16} xr[row+i]
            const int row = t >> 3, c8 = t & 7;
            float S[8] = {};
            #pragma unroll
            for (int i = 0; i < 17; ++i) {
                const u16x8 h = *reinterpret_cast<const u16x8*>(xr + (row + i) * 160 + c8 * 16);
                #pragma unroll
                for (int j = 0; j < 8; ++j) S[j] += bf2f(h[j]);
            }
            u16x8 o;
            #pragma unroll
            for (int j = 0; j < 8; ++j) o[j] = f2bf(S[j] * inv17);
            *reinterpret_cast<u16x8*>(As + row * 128 + ((c8 ^ (row & 7)) * 16)) = o;
        }
        __syncthreads();
        if (kt == 0) {   // issue x loads for kt=1 (hidden under MFMA)
            xa0 = *reinterpret_cast<const float4*>(x + (size_t)rwA * INFEAT + 64 + c8A * 8);
            xa1 = *reinterpret_cast<const float4*>(x + (size_t)rwA * INFEAT + 64 + c8A * 8 + 4);
            if (vB) {
                xb0 = *reinterpret_cast<const float4*>(x + (size_t)rwB * INFEAT + 64 + c8B * 8);
                xb1 = *reinterpret_cast<const float4*>(x + (size_t)rwB * INFEAT + 64 + c8B * 8 + 4);
            }
        }
        #pragma unroll
        for (int kk = 0; kk < 2; ++kk) {
            const int klog = kk * 64 + ((lane >> 4) << 4);
            bf16x8 af[2];
            #pragma unroll
            for (int mi = 0; mi < 2; ++mi) {
                const int row = wr + mi * 16 + (lane & 15);
                af[mi] = *reinterpret_cast<const bf16x8*>(As + row * 128 + (klog ^ ((row & 7) << 4)));
            }
            #pragma unroll
            for (int ny = 0; ny < 2; ++ny)
                #pragma unroll
                for (int ni = 0; ni < 2; ++ni) {
                    const int row = ny * 128 + wc + ni * 16 + (lane & 15);
                    const bf16x8 bv = *reinterpret_cast<const bf16x8*>(Bs + row * 128 + (klog ^ ((row & 7) << 4)));
                    #pragma unroll
                    for (int mi = 0; mi < 2; ++mi)
                        acc[ny][mi][ni] = __builtin_amdgcn_mfma_f32_16x16x32_bf16(af[mi], bv, acc[ny][mi][ni], 0, 0, 0);
                }
        }
        // no trailing barrier: next-kt xr writes are disjoint from As/Bs; B-GLD16
        // sits behind the next sync(a) which no wave passes until MFMA completes.
    }

    // epilogue: bias, store A (bf16), BN partials -> global atomic accumulation
    float* sS  = (float*)smem;            // [8][64] (xr region, reads done)
    float* s2S = (float*)(smem + 2048);   // [8][64]
    #pragma unroll
    for (int ny = 0; ny < 2; ++ny)
        #pragma unroll
        for (int ni = 0; ni < 2; ++ni) {
            const int colL = ny * 128 + wc + ni * 16 + (lane & 15);
            const float bv = b1[colL];
            float sv = 0.f, s2v = 0.f;
            #pragma unroll
            for (int mi = 0; mi < 2; ++mi)
                #pragma unroll
                for (int r = 0; r < 4; ++r) {
                    const int row = bm + wr + mi * 16 + ((lane >> 4) << 2) + r;
                    if (row < NN) {
                        const float val = acc[ny][mi][ni][r] + bv;
                        A[(size_t)row * 256 + colL] = f2bf(val);
                        sv += val; s2v += val * val;
                    }
                }
            sv  += __shfl_xor(sv, 16);  sv  += __shfl_xor(sv, 32);
            s2v += __shfl_xor(s2v, 16); s2v += __shfl_xor(s2v, 32);
            if (lane < 16) {
                sS [wave * 64 + ny * 32 + ni * 16 + lane] = sv;
                s2S[wave * 64 + ny * 32 + ni * 16 + lane] = s2v;
            }
        }
    __syncthreads();
    if (t < 256) {
        const int col = t;
        const int idx = (col >> 7) * 32 + ((col >> 4) & 1) * 16 + (col & 15);
        const int wcx = (col & 127) >> 5;
        atomicAdd(&asum[col],       sS [wcx * 64 + idx] + sS [(wcx + 4) * 64 + idx]);
        atomicAdd(&asum[512 + col], s2S[wcx * 64 + idx] + s2S[(wcx + 4) * 64 + idx]);
    }
}

// ===== kernel 3: h2 = relu( agg(relu(bn(A))) @ W2 + b2 ), dots, P, edge outputs =====
// Out-tile M=104; GEMM rows = 128 (halo recompute). Full Bs. T14 A-prefetch.
// 2 barriers per kt (trailing barrier proven redundant).
__global__ __launch_bounds__(512, 2) void k_fused2(const ushort* __restrict__ A,
    const ushort* __restrict__ W2t, const float* __restrict__ gamma,
    const float* __restrict__ beta, const float* __restrict__ b2,
    const float* __restrict__ Wl, const float* __restrict__ bl,
    const float* __restrict__ asum, float* __restrict__ out)
{
    __shared__ alignas(16) char smem[23040 + 16384 + 32768 + 2048];
    char* xr   = smem;                            // 144 x 160B (bf16 bnrelu'd, padded)
    char* As   = smem + 23040;                    // 128 x 128B swizzled
    char* Bs   = smem + 23040 + 16384;            // 256 x 128B swizzled (full N)
    float* ssS = (float*)(smem + 23040 + 16384 + 32768);  // sc[256] | sh[256]

    const int b = blockIdx.x, t = threadIdx.x;
    const int wave = t >> 6, lane = t & 63;
    const int wr  = (wave >> 1) * 32;       // 4 row-quads
    const int wcx = (wave & 1);             // 2 col groups of 64 within 128-half
    const int v0 = b * MOUT;
    const float inv17 = 1.0f / 17.0f;

    if (t < 256) {
        const float invn = 1.0f / (float)NN;
        const float mu  = asum[t] * invn;
        const float var = asum[512 + t] * invn - mu * mu;
        const float sc  = gamma[t] * rsqrtf(var + EPSF);
        ssS[t]       = sc;
        ssS[256 + t] = beta[t] - mu * sc;
    }
    __syncthreads();

    f32x4 acc[2][2][4] = {};   // [h][mi][ni]

    // chunk mapping: c = r3*512 + t; row = c>>3, c8 = c&7 (c < 1152)
    const int rg0 = wrapN(v0 - 16 + (t >> 3)),          f80 = (t & 7) * 8;
    const int rg1 = wrapN(v0 - 16 + ((512 + t) >> 3)),  f81 = ((512 + t) & 7) * 8;
    const int rg2 = wrapN(v0 - 16 + ((1024 + t) >> 3)), f82 = ((1024 + t) & 7) * 8;
    const bool v2 = (1024 + t) < 1152;

    // prologue: load A chunks for kt=0
    u16x8 aq0 = *reinterpret_cast<const u16x8*>(A + (size_t)rg0 * 256 + f80);
    u16x8 aq1 = *reinterpret_cast<const u16x8*>(A + (size_t)rg1 * 256 + f81);
    u16x8 aq2 = v2 ? *reinterpret_cast<const u16x8*>(A + (size_t)rg2 * 256 + f82)
                   : u16x8{};

    #pragma unroll
    for (int kt = 0; kt < 4; ++kt) {
        const int k0 = kt * 64;
        // bnrelu + write staged A -> xr
        *reinterpret_cast<u16x8*>(xr + (t >> 3) * 160 + (t & 7) * 16)
            = bnrelu8(aq0, ssS, k0 + f80);
        *reinterpret_cast<u16x8*>(xr + ((512 + t) >> 3) * 160 + ((512 + t) & 7) * 16)
            = bnrelu8(aq1, ssS, k0 + f81);
        if (v2)
            *reinterpret_cast<u16x8*>(xr + ((1024 + t) >> 3) * 160 + ((1024 + t) & 7) * 16)
                = bnrelu8(aq2, ssS, k0 + f82);
        __syncthreads();
        #pragma unroll
        for (int it = 0; it < 4; ++it) {   // stage B(kt) — drain hidden under As-build
            const int cb = (it * 8 + wave) * 64 + lane;
            const int row = cb >> 3;
            const int lk = (cb & 7) ^ (row & 7);
            GLD16(W2t + (size_t)row * 256 + k0 + lk * 8, Bs + (it * 8 + wave) * 1024);
        }
        {   // build As: 2 rows/thread, rolling 17-tap (512 threads)
            const int q = t >> 3, c8 = t & 7;
            const int r0 = 2 * q;
            float S[8] = {};
            #pragma unroll
            for (int i = 0; i < 17; ++i) {
                const u16x8 h = *reinterpret_cast<const u16x8*>(xr + (r0 + i) * 160 + c8 * 16);
                #pragma unroll
                for (int j = 0; j < 8; ++j) S[j] += bf2f(h[j]);
            }
            u16x8 o;
            #pragma unroll
            for (int j = 0; j < 8; ++j) o[j] = f2bf(S[j] * inv17);
            *reinterpret_cast<u16x8*>(As + r0 * 128 + ((c8 ^ (r0 & 7)) * 16)) = o;
            const u16x8 ha = *reinterpret_cast<const u16x8*>(xr + (r0 + 17) * 160 + c8 * 16);
            const u16x8 hs = *reinterpret_cast<const u16x8*>(xr + r0 * 160 + c8 * 16);
            #pragma unroll
            for (int j = 0; j < 8; ++j) S[j] += bf2f(ha[j]) - bf2f(hs[j]);
            const int r1 = r0 + 1;
            #pragma unroll
            for (int j = 0; j < 8; ++j) o[j] = f2bf(S[j] * inv17);
            *reinterpret_cast<u16x8*>(As + r1 * 128 + ((c8 ^ (r1 & 7)) * 16)) = o;
        }
        __syncthreads();   // As + full Bs ready
        if (kt < 3) {      // issue A loads for kt+1 (hidden under MFMA)
            const int k1 = k0 + 64;
            aq0 = *reinterpret_cast<const u16x8*>(A + (size_t)rg0 * 256 + k1 + f80);
            aq1 = *reinterpret_cast<const u16x8*>(A + (size_t)rg1 * 256 + k1 + f81);
            if (v2)
                aq2 = *reinterpret_cast<const u16x8*>(A + (size_t)rg2 * 256 + k1 + f82);
        }
        #pragma unroll
        for (int kk = 0; kk < 2; ++kk) {
            const int klog = kk * 64 + ((lane >> 4) << 4);
            bf16x8 af[2];
            #pragma unroll
            for (int mi = 0; mi < 2; ++mi) {
                const int row = wr + mi * 16 + (lane & 15);
                af[mi] = *reinterpret_cast<const bf16x8*>(As + row * 128 + (klog ^ ((row & 7) << 4)));
            }
            #pragma unroll
            for (int h = 0; h < 2; ++h)
                #pragma unroll
                for (int ni = 0; ni < 4; ++ni) {
                    const int rl = h * 128 + wcx * 64 + ni * 16 + (lane & 15);
                    const bf16x8 bv = *reinterpret_cast<const bf16x8*>(Bs + rl * 128 + (klog ^ ((rl & 7) << 4)));
                    #pragma unroll
                    for (int mi = 0; mi < 2; ++mi)
                        acc[h][mi][ni] = __builtin_amdgcn_mfma_f32_16x16x32_bf16(af[mi], bv, acc[h][mi][ni], 0, 0, 0);
                }
        }
        // no trailing barrier (same argument as k_fused1)
    }

    // epilogue: relu + per-row dots with Wl -> uL/wL in LDS (no global round-trip)
    float b2v[2][4], wav[2][4], wbv[2][4];
    #pragma unroll
    for (int h = 0; h < 2; ++h)
        #pragma unroll
        for (int ni = 0; ni < 4; ++ni) {
            const int col = h * 128 + wcx * 64 + ni * 16 + (lane & 15);
            b2v[h][ni] = b2[col];
            wav[h][ni] = Wl[col];
            wbv[h][ni] = Wl[256 + col];
        }
    float* uW = (float*)smem;            // [2][128] (xr region, reads done)
    float* wW = (float*)(smem + 1024);   // [2][128]
    float* uL = (float*)(smem + 23040);         // [128]
    float* wL = (float*)(smem + 23040 + 512);   // [128]
    float* PS = (float*)(smem + 23040 + 1024);  // [112]
    #pragma unroll
    for (int mi = 0; mi < 2; ++mi)
        #pragma unroll
        for (int r = 0; r < 4; ++r) {
            float pu = 0.f, pw = 0.f;
            #pragma unroll
            for (int h = 0; h < 2; ++h)
                #pragma unroll
                for (int ni = 0; ni < 4; ++ni) {
                    const float hv = fmaxf(acc[h][mi][ni][r] + b2v[h][ni], 0.f);
                    pu += hv * wav[h][ni];
                    pw += hv * wbv[h][ni];
                }
            pu += __shfl_xor(pu, 1); pu += __shfl_xor(pu, 2);
            pu += __shfl_xor(pu, 4); pu += __shfl_xor(pu, 8);
            pw += __shfl_xor(pw, 1); pw += __shfl_xor(pw, 2);
            pw += __shfl_xor(pw, 4); pw += __shfl_xor(pw, 8);
            if ((lane & 15) == 0) {
                const int rl = wr + mi * 16 + ((lane >> 4) << 2) + r;
                uW[wcx * 128 + rl] = pu;
                wW[wcx * 128 + rl] = pw;
            }
        }
    __syncthreads();
    if (t < 128) {
        uL[t] = uW[t] + uW[128 + t];
        wL[t] = wW[t] + wW[128 + t];
    }
    __syncthreads();

    // P for nodes [v0, v0+112): PS[i] uses uL[i..i+16], wL[i+8]
    if (t < 112) {
        const int l = t + 8;
        float s = uL[l] + 16.0f * wL[l];
        #pragma unroll
        for (int o = 1; o <= 8; ++o)
            s += uL[l + o] + uL[l - o];
        PS[t] = s;
    }
    __syncthreads();

    // edge outputs for nodes [v0, v0+104)
    const float blv = bl[0];
    #pragma unroll
    for (int rr = 0; rr < 4; ++rr) {
        const int q = t + rr * 512;              // [0, 2048); valid < 1664
        if (q >= 1664) continue;
        const int half = (q >= 832) ? 1 : 0;
        const int e = q - half * 832;
        const int i = e >> 3, off = e & 7;
        const int v = v0 + i;
        if (v >= NN) continue;
        if (!half) {   // forward edge (v -> v+1+off): P[v] + w[v+1+off]
            out[v * 8 + off] = sigmoidf_((PS[i] + wL[i + 9 + off]) * inv17 + blv);
        } else {       // reverse edge owned by tt = v: P[v+1+off] + w[v]
            out[NK + v * 8 + off] = sigmoidf_((PS[i + 1 + off] + wL[i + 8]) * inv17 + blv);
        }
    }
}

// ---------------- launch ----------------
extern "C" void kernel_launch(void* const* d_in, const int* in_sizes, int n_in,
                              void* d_out, int out_size, void* d_ws, size_t ws_size,
                              hipStream_t stream)
{
    const float* x      = (const float*)d_in[0];
    const float* W1     = (const float*)d_in[1];
    const float* b1     = (const float*)d_in[2];
    const float* gamma1 = (const float*)d_in[3];
    const float* beta1  = (const float*)d_in[4];
    const float* W2     = (const float*)d_in[5];
    const float* b2     = (const float*)d_in[6];
    const float* Wl     = (const float*)d_in[7];
    const float* bl     = (const float*)d_in[8];
    float* out = (float*)d_out;

    float*    asum = (float*)d_ws;                   // [1024]
    ushort*   A    = (ushort*)(asum + 1024);         // [NN,256] bf16
    ushort*   W1t  = A + (size_t)NN * 256;           // [256,128]
    ushort*   W2t  = W1t + 256 * 128;                // [256,256]

    k_prep  <<<49,   512, 0, stream>>>(W1, W2, W1t, W2t, asum);
    k_fused1<<<NT1,  512, 0, stream>>>(x, W1t, b1, A, asum);
    k_fused2<<<NT2B, 512, 0, stream>>>(A, W2t, gamma1, beta1, b2, Wl, bl, asum, out);
}